// Round 4
// baseline (235.160 us; speedup 1.0000x reference)
//
#include <hip/hip_runtime.h>

// ---------------------------------------------------------------------------
// CrossAttention (BLT-style patch cross-attention), MI355X gfx950
// B=2, S=4096, P=1024, D=1024, H=16, dh=64
//
// Round 11 (softmax VALU + MFMA chain ILP):
//   - EXP2 forced to a single v_exp_f32 via inline asm (R10 counter math
//     showed ~2.8x VALU inflation consistent with an OCML exp2 fallback)
//   - QK and PV MFMA loops interchanged so consecutive MFMAs hit alternating
//     accumulators (sa0/sa1, oacc0/oacc1) -> dep-chain stalls halve, 0 VGPR
//   - everything else unchanged from R10 (32x32 swapped-QK attn, frag-linear
//     K/V, dbuf gll staging + counted vmcnt, swizzled GEMMs)
// ---------------------------------------------------------------------------

#define B_ 2
#define S_ 4096
#define P_ 1024
#define D_ 1024
#define H_ 16
#define DH_ 64

#define NCONV 14336   /* convert blocks: (2097152+524288+4*262144)/256 */

typedef __attribute__((ext_vector_type(8))) short short8;
typedef __attribute__((ext_vector_type(4))) float f32x4;
typedef __attribute__((ext_vector_type(16))) float f32x16;

#define KSCALE 0.18033688011112042f  /* 1/sqrt(64) * log2(e) */

// single-instruction 2^x (input pre-scaled by log2e; range safe for scores)
static __device__ __forceinline__ float exp2_raw(float x) {
    float r;
    asm("v_exp_f32 %0, %1" : "=v"(r) : "v"(x));
    return r;
}

static __device__ __forceinline__ unsigned short f2bf(float f) {
    unsigned int u = __float_as_uint(f);
    u += 0x7FFFu + ((u >> 16) & 1u);   // round-to-nearest-even
    return (unsigned short)(u >> 16);
}

// packed f32->bf16 pair (RTNE), no builtin on gfx950
static __device__ __forceinline__ unsigned int cvtpk(float lo, float hi) {
    unsigned int r;
    asm("v_cvt_pk_bf16_f32 %0, %1, %2" : "=v"(r) : "v"(lo), "v"(hi));
    return r;
}

// x' = [x.row0, y.row0] ; y' = [x.row1, y.row1]  (rows = 32-lane halves)
static __device__ __forceinline__ void plswap(unsigned int& x, unsigned int& y) {
    asm volatile("v_permlane32_swap_b32 %0, %1" : "+v"(x), "+v"(y));
}

// async 16B global -> LDS (wave-uniform lds base + lane*16; global per-lane)
static __device__ __forceinline__ void gll16(const unsigned short* g,
                                             const unsigned short* l) {
    __builtin_amdgcn_global_load_lds(
        (const __attribute__((address_space(1))) unsigned int*)g,
        (__attribute__((address_space(3))) unsigned int*)l,
        16, 0, 0);
}

// ---------------------------------------------------------------------------
// fused fp32 -> bf16 conversion of all six tensors + cumsum (single launch)
// ---------------------------------------------------------------------------
__global__ __launch_bounds__(256) void xattn_convert_all(
    const float* __restrict__ queries, const float* __restrict__ patches,
    const float* __restrict__ wq, const float* __restrict__ wk,
    const float* __restrict__ wv, const float* __restrict__ wo,
    unsigned short* __restrict__ qb, unsigned short* __restrict__ pb,
    unsigned short* __restrict__ wqb, unsigned short* __restrict__ wkb,
    unsigned short* __restrict__ wvb, unsigned short* __restrict__ wob,
    const int* __restrict__ bounds, int* __restrict__ pidx) {
    if (blockIdx.x >= NCONV) {
        // ---- cumsum path: one block per batch, 256 threads x 16 elems ----
        __shared__ int sdata[256];
        int b = blockIdx.x - NCONV;
        int t = threadIdx.x;
        const int* src = bounds + b * S_ + t * 16;
        int vals[16];
        int run = 0;
#pragma unroll
        for (int i = 0; i < 16; ++i) { run += src[i]; vals[i] = run; }
        sdata[t] = run;
        __syncthreads();
        for (int off = 1; off < 256; off <<= 1) {
            int v = (t >= off) ? sdata[t - off] : 0;
            __syncthreads();
            sdata[t] += v;
            __syncthreads();
        }
        int prefix = (t > 0) ? sdata[t - 1] : 0;
        int* dst = pidx + b * S_ + t * 16;
#pragma unroll
        for (int i = 0; i < 16; ++i) dst[i] = prefix + vals[i];
        return;
    }
    // ---- convert path ----
    const int NQ = (B_ * S_ * D_) / 4;      // 2097152
    const int NP = (B_ * P_ * D_) / 4;      // 524288
    const int NW = (D_ * D_) / 4;           // 262144
    int i = blockIdx.x * 256 + threadIdx.x;
    const float* src;
    unsigned short* dst;
    int j;
    if (i < NQ) { src = queries; dst = qb; j = i; }
    else if (i < NQ + NP) { src = patches; dst = pb; j = i - NQ; }
    else {
        int k = i - NQ - NP;
        int wsel = k >> 18;                  // NW = 2^18
        j = k & (NW - 1);
        if (wsel == 0) { src = wq; dst = wqb; }
        else if (wsel == 1) { src = wk; dst = wkb; }
        else if (wsel == 2) { src = wv; dst = wvb; }
        else { src = wo; dst = wob; }
    }
    float4 v = ((const float4*)src)[j];
    ushort4 o;
    o.x = f2bf(v.x); o.y = f2bf(v.y); o.z = f2bf(v.z); o.w = f2bf(v.w);
    ((ushort4*)dst)[j] = o;
}

// ---------------------------------------------------------------------------
// Fused QKV projection: 128x128 tile, dbuf gll staging + counted vmcnt,
// XOR-swizzled LDS, BK=32, 4 waves.
// Grid dim3(8, 96): y<64 -> Q-proj (M=8192, bf16 out * KSCALE, row-major)
//                   y in [64,80) -> K-proj -> FRAGMENT-LINEAR Kf
//                   y in [80,96) -> V-proj -> FRAGMENT-LINEAR Vf
// Fragment-linear layouts (per b,h,ptile of 64 patches; 4096 shorts each):
//   Kf: [at(2)][ks(4)][lane(64)][j(8)]   lane=((k>>3)&1)*32+(p&31), j=k&7,
//       at=(p>>5)&1, ks=(k>>4)&3   (A-operand of S^T = mfma(K,Q))
//   Vf: [dt(2)][ps(4)][lane(64)][j(8)]   lane=((p>>3)&1)*32+(d&31), j=p&7,
//       dt=d>>5, ps=(p>>4)&3        (B-operand of PV)
// ---------------------------------------------------------------------------
__global__ __launch_bounds__(256) void xattn_gemm_qkv(
    const unsigned short* __restrict__ qb, const unsigned short* __restrict__ pb,
    const unsigned short* __restrict__ wqb, const unsigned short* __restrict__ wkb,
    const unsigned short* __restrict__ wvb,
    const float* __restrict__ bq, const float* __restrict__ bk,
    const float* __restrict__ bv,
    unsigned short* __restrict__ Qout, unsigned short* __restrict__ Kout,
    unsigned short* __restrict__ Vout) {
    const int K = 1024, N = 1024;
    const int byy = blockIdx.y;
    int z, my;
    if (byy < 64)      { z = 0; my = byy; }
    else if (byy < 80) { z = 1; my = byy - 64; }
    else               { z = 2; my = byy - 80; }
    const unsigned short* A = (z == 0) ? qb : pb;
    const unsigned short* W = (z == 0) ? wqb : ((z == 1) ? wkb : wvb);
    const float* bias = (z == 0) ? bq : ((z == 1) ? bk : bv);

    __shared__ unsigned short As[2][128 * 32];
    __shared__ unsigned short Bs[2][128 * 32];

    const int m0 = my * 128;
    const int n0 = blockIdx.x * 128;
    const int t = threadIdx.x;
    const int w = t >> 6;
    const int l = t & 63;
    const int fr = l & 15, fq = l >> 4;
    const int wr = w >> 1, wc = w & 1;

    const int r0s = t >> 2;
    const int csw = ((t & 3) ^ ((t >> 3) & 3)) * 8;   // pre-swizzled source
    const unsigned short* Ap0 = A + (size_t)(m0 + r0s) * K + csw;
    const unsigned short* Ap1 = A + (size_t)(m0 + 64 + r0s) * K + csw;
    const unsigned short* Wp0 = W + (size_t)(n0 + r0s) * K + csw;
    const unsigned short* Wp1 = W + (size_t)(n0 + 64 + r0s) * K + csw;

    const int gsw = (fq ^ ((fr >> 1) & 3)) * 8;       // swizzled read granule

    f32x4 acc[4][4];
#pragma unroll
    for (int i = 0; i < 4; ++i)
#pragma unroll
        for (int j = 0; j < 4; ++j) acc[i][j] = (f32x4){0.f, 0.f, 0.f, 0.f};

    // prologue: stage K-step 0 into buffer 0
    gll16(Ap0, &As[0][w * 512]);
    gll16(Ap1, &As[0][2048 + w * 512]);
    gll16(Wp0, &Bs[0][w * 512]);
    gll16(Wp1, &Bs[0][2048 + w * 512]);

    for (int kt = 0; kt < 32; ++kt) {
        __builtin_amdgcn_s_barrier();     // prev iter's readers done
        if (kt + 1 < 32) {
            const int nb = (kt + 1) & 1;
            const int ks = (kt + 1) * 32;
            gll16(Ap0 + ks, &As[nb][w * 512]);
            gll16(Ap1 + ks, &As[nb][2048 + w * 512]);
            gll16(Wp0 + ks, &Bs[nb][w * 512]);
            gll16(Wp1 + ks, &Bs[nb][2048 + w * 512]);
            asm volatile("s_waitcnt vmcnt(4)" ::: "memory");
        } else {
            asm volatile("s_waitcnt vmcnt(0)" ::: "memory");
        }
        __builtin_amdgcn_sched_barrier(0);
        __builtin_amdgcn_s_barrier();     // all waves' step-kt stage complete

        const unsigned short* Ac = As[kt & 1];
        const unsigned short* Bc = Bs[kt & 1];
        short8 af[4], bf[4];
#pragma unroll
        for (int i = 0; i < 4; ++i)
            af[i] = *(const short8*)&Ac[(wr * 64 + i * 16 + fr) * 32 + gsw];
#pragma unroll
        for (int j = 0; j < 4; ++j)
            bf[j] = *(const short8*)&Bc[(wc * 64 + j * 16 + fr) * 32 + gsw];
        __builtin_amdgcn_s_setprio(1);
#pragma unroll
        for (int i = 0; i < 4; ++i)
#pragma unroll
            for (int j = 0; j < 4; ++j)
                acc[i][j] = __builtin_amdgcn_mfma_f32_16x16x32_bf16(af[i], bf[j], acc[i][j], 0, 0, 0);
        __builtin_amdgcn_s_setprio(0);
    }

#pragma unroll
    for (int j = 0; j < 4; ++j) {
        int n = n0 + wc * 64 + j * 16 + fr;
        float bvv = bias[n];
#pragma unroll
        for (int i = 0; i < 4; ++i) {
            int mbase = m0 + wr * 64 + i * 16 + fq * 4;
#pragma unroll
            for (int r = 0; r < 4; ++r) {
                float val = acc[i][j][r] + bvv;
                int m = mbase + r;
                if (z == 0) {
                    Qout[(size_t)m * N + n] = f2bf(val * KSCALE);
                } else if (z == 1) {
                    int bb = m >> 10, p = m & (P_ - 1);
                    int hh = n >> 6, k = n & 63;
                    size_t base = ((size_t)((bb * H_ + hh) * 16 + (p >> 6))) * 4096;
                    int off = (((p >> 5) & 1) * 4 + (k >> 4)) * 512 +
                              (((k >> 3) & 1) * 32 + (p & 31)) * 8 + (k & 7);
                    Kout[base + off] = f2bf(val);
                } else {
                    int bb = m >> 10, p = m & (P_ - 1);
                    int hh = n >> 6, d = n & 63;
                    size_t base = ((size_t)((bb * H_ + hh) * 16 + (p >> 6))) * 4096;
                    int off = ((d >> 5) * 4 + ((p >> 4) & 3)) * 512 +
                              ((((p >> 3) & 1) * 32) + (d & 31)) * 8 + (p & 7);
                    Vout[base + off] = f2bf(val);
                }
            }
        }
    }
}

// ---------------------------------------------------------------------------
// 128x128-tile GEMM, dbuf gll staging + counted vmcnt, XOR-swizzled LDS,
// fp32 out (O projection). Unchanged from R9.
// ---------------------------------------------------------------------------
__global__ __launch_bounds__(256) void xattn_gemm_o(
    const unsigned short* __restrict__ A,
    const unsigned short* __restrict__ W,
    const float* __restrict__ bias,
    float* __restrict__ Cout) {
    const int K = 1024, N = 1024;
    __shared__ unsigned short As[2][128 * 32];
    __shared__ unsigned short Bs[2][128 * 32];

    const int m0 = blockIdx.y * 128;
    const int n0 = blockIdx.x * 128;
    const int t = threadIdx.x;
    const int w = t >> 6;
    const int l = t & 63;
    const int fr = l & 15, fq = l >> 4;
    const int wr = w >> 1, wc = w & 1;

    const int r0s = t >> 2;
    const int csw = ((t & 3) ^ ((t >> 3) & 3)) * 8;   // pre-swizzled source
    const unsigned short* Ap0 = A + (size_t)(m0 + r0s) * K + csw;
    const unsigned short* Ap1 = A + (size_t)(m0 + 64 + r0s) * K + csw;
    const unsigned short* Wp0 = W + (size_t)(n0 + r0s) * K + csw;
    const unsigned short* Wp1 = W + (size_t)(n0 + 64 + r0s) * K + csw;

    const int gsw = (fq ^ ((fr >> 1) & 3)) * 8;       // swizzled read granule

    f32x4 acc[4][4];
#pragma unroll
    for (int i = 0; i < 4; ++i)
#pragma unroll
        for (int j = 0; j < 4; ++j) acc[i][j] = (f32x4){0.f, 0.f, 0.f, 0.f};

    // prologue: stage K-step 0 into buffer 0
    gll16(Ap0, &As[0][w * 512]);
    gll16(Ap1, &As[0][2048 + w * 512]);
    gll16(Wp0, &Bs[0][w * 512]);
    gll16(Wp1, &Bs[0][2048 + w * 512]);

    for (int kt = 0; kt < 32; ++kt) {
        __builtin_amdgcn_s_barrier();
        if (kt + 1 < 32) {
            const int nb = (kt + 1) & 1;
            const int ks = (kt + 1) * 32;
            gll16(Ap0 + ks, &As[nb][w * 512]);
            gll16(Ap1 + ks, &As[nb][2048 + w * 512]);
            gll16(Wp0 + ks, &Bs[nb][w * 512]);
            gll16(Wp1 + ks, &Bs[nb][2048 + w * 512]);
            asm volatile("s_waitcnt vmcnt(4)" ::: "memory");
        } else {
            asm volatile("s_waitcnt vmcnt(0)" ::: "memory");
        }
        __builtin_amdgcn_sched_barrier(0);
        __builtin_amdgcn_s_barrier();

        const unsigned short* Ac = As[kt & 1];
        const unsigned short* Bc = Bs[kt & 1];
        short8 af[4], bf[4];
#pragma unroll
        for (int i = 0; i < 4; ++i)
            af[i] = *(const short8*)&Ac[(wr * 64 + i * 16 + fr) * 32 + gsw];
#pragma unroll
        for (int j = 0; j < 4; ++j)
            bf[j] = *(const short8*)&Bc[(wc * 64 + j * 16 + fr) * 32 + gsw];
        __builtin_amdgcn_s_setprio(1);
#pragma unroll
        for (int i = 0; i < 4; ++i)
#pragma unroll
            for (int j = 0; j < 4; ++j)
                acc[i][j] = __builtin_amdgcn_mfma_f32_16x16x32_bf16(af[i], bf[j], acc[i][j], 0, 0, 0);
        __builtin_amdgcn_s_setprio(0);
    }

#pragma unroll
    for (int j = 0; j < 4; ++j) {
        int n = n0 + wc * 64 + j * 16 + fr;
        float bvv = bias[n];
#pragma unroll
        for (int i = 0; i < 4; ++i) {
            int mbase = m0 + wr * 64 + i * 16 + fq * 4;
#pragma unroll
            for (int r = 0; r < 4; ++r)
                Cout[(size_t)(mbase + r) * N + n] = acc[i][j][r] + bvv;
        }
    }
}

// ---------------------------------------------------------------------------
// MFMA flash attention, round 11: 32x32x16 swapped-QK, in-register softmax,
// raw v_exp_f32, interleaved accumulator chains.
// Block = 4 waves x 32 q-rows = 128 q. Per 64-patch tile, per wave:
//   S^T = mfma(K,Q): ks-outer, at-inner -> sa0/sa1 alternate (chain ILP 2)
//   exp2 (1 instr) + boundary mask + lsum
//   P -> bf16 A-frags: 16 v_cvt_pk_bf16_f32 + 8 v_permlane32_swap_b32
//   PV: ps-outer, dt-inner -> oacc0/oacc1 alternate (chain ILP 2)
// All LDS reads lane-linear ds_read_b128 (zero bank conflicts by design).
// ---------------------------------------------------------------------------
__global__ __launch_bounds__(256) void xattn_attn_mfma(
    const unsigned short* __restrict__ Qb,   // [B*S][D] bf16 (pre-scaled)
    const unsigned short* __restrict__ Kf,   // frag-linear (see gemm_qkv)
    const unsigned short* __restrict__ Vf,   // frag-linear
    const int* __restrict__ pidx,
    unsigned short* __restrict__ Ob) {       // [B*S][D] bf16
    __shared__ unsigned short Ks[2][4096];
    __shared__ unsigned short Vs[2][4096];

    const int q0 = (31 - blockIdx.x) * 128;  // LPT: heavy blocks first
    const int h = blockIdx.y;
    const int b = blockIdx.z;
    const int t = threadIdx.x;
    const int w = t >> 6, l = t & 63;
    const int lq = l & 31, lh = l >> 5;
    const int qw = q0 + w * 32;

    // Q B-frags (col = lq, k = ks*16 + lh*8 + j), loaded once
    const unsigned short* qrow =
        Qb + (size_t)(b * S_ + qw + lq) * D_ + h * DH_ + lh * 8;
    short8 qf[4];
#pragma unroll
    for (int ks = 0; ks < 4; ++ks) qf[ks] = *(const short8*)(qrow + ks * 16);

    const int prow = pidx[b * S_ + qw + lq];        // this lane's q row
    const int limit = pidx[b * S_ + q0 + 127];      // monotone in s
    const int ntiles = (min(limit, P_ - 1) + 64) >> 6;
    const int nfull = (pidx[b * S_ + q0] + 1) >> 6; // tiles needing no mask

    float l4[4] = {0.f, 0.f, 0.f, 0.f};
    f32x16 oacc0 = {}, oacc1 = {};

    // staging: wave w moves 1KB chunks 2w, 2w+1 of each 8KB frag tile
    const unsigned short* kfb =
        Kf + (size_t)((b * H_ + h) * 16) * 4096 + (2 * w) * 512 + l * 8;
    const unsigned short* vfb =
        Vf + (size_t)((b * H_ + h) * 16) * 4096 + (2 * w) * 512 + l * 8;

    // prologue: stage tile 0 into buffer 0
    gll16(kfb, &Ks[0][(2 * w) * 512]);
    gll16(kfb + 512, &Ks[0][(2 * w + 1) * 512]);
    gll16(vfb, &Vs[0][(2 * w) * 512]);
    gll16(vfb + 512, &Vs[0][(2 * w + 1) * 512]);

    for (int kt = 0; kt < ntiles; ++kt) {
        // B1: all waves done reading buf[kt&1 ^1] -> safe to refill
        __builtin_amdgcn_s_barrier();
        if (kt + 1 < ntiles) {
            const int nb = (kt + 1) & 1;
            const unsigned short* kn = kfb + (size_t)(kt + 1) * 4096;
            const unsigned short* vn = vfb + (size_t)(kt + 1) * 4096;
            gll16(kn, &Ks[nb][(2 * w) * 512]);
            gll16(kn + 512, &Ks[nb][(2 * w + 1) * 512]);
            gll16(vn, &Vs[nb][(2 * w) * 512]);
            gll16(vn + 512, &Vs[nb][(2 * w + 1) * 512]);
            asm volatile("s_waitcnt vmcnt(4)" ::: "memory");
        } else {
            asm volatile("s_waitcnt vmcnt(0)" ::: "memory");
        }
        __builtin_amdgcn_sched_barrier(0);
        // B2: every wave's tile-kt stage is complete
        __builtin_amdgcn_s_barrier();

        const unsigned short* Kc = Ks[kt & 1];
        const unsigned short* Vc = Vs[kt & 1];
        const int c0 = kt * 64;

        // S^T = K . Q^T  (rows p via regs, cols q = lq)
        // ks-outer / at-inner: sa0/sa1 alternate -> dep-chain ILP 2
        f32x16 sa0 = {}, sa1 = {};
        __builtin_amdgcn_s_setprio(1);
#pragma unroll
        for (int ks = 0; ks < 4; ++ks) {
            short8 kfr0 = *(const short8*)&Kc[(0 * 4 + ks) * 512 + l * 8];
            short8 kfr1 = *(const short8*)&Kc[(1 * 4 + ks) * 512 + l * 8];
            sa0 = __builtin_amdgcn_mfma_f32_32x32x16_bf16(kfr0, qf[ks], sa0, 0, 0, 0);
            sa1 = __builtin_amdgcn_mfma_f32_32x32x16_bf16(kfr1, qf[ks], sa1, 0, 0, 0);
        }
        __builtin_amdgcn_s_setprio(0);

        // exp2 + boundary mask + lsum (p-row of reg r = (r&3)+8*(r>>2)+4*lh)
        if (kt >= nfull) {
#pragma unroll
            for (int r = 0; r < 16; ++r) {
                const int pg0 = c0 + (r & 3) + 8 * (r >> 2) + 4 * lh;
                float p0 = exp2_raw(sa0[r]);
                p0 = (pg0 > prow) ? 0.f : p0;
                sa0[r] = p0;
                l4[r & 3] += p0;
                float p1 = exp2_raw(sa1[r]);
                p1 = (pg0 + 32 > prow) ? 0.f : p1;
                sa1[r] = p1;
                l4[r & 3] += p1;
            }
        } else {
#pragma unroll
            for (int r = 0; r < 16; ++r) {
                float p0 = exp2_raw(sa0[r]);
                sa0[r] = p0;
                l4[r & 3] += p0;
                float p1 = exp2_raw(sa1[r]);
                sa1[r] = p1;
                l4[r & 3] += p1;
            }
        }

        // pack P into PV A-frags: word m of step ps = bf16 pair
        // p = ps*16 + lh*8 + 2m (+1); own-half pack + permlane32_swap
        short8 pa[4];
#pragma unroll
        for (int ps = 0; ps < 4; ++ps) {
            unsigned int X0, Y0, X1, Y1;
            if (ps < 2) {
                const int rA = (ps & 1) * 8;
                X0 = cvtpk(sa0[rA + 0], sa0[rA + 1]);
                Y0 = cvtpk(sa0[rA + 4], sa0[rA + 5]);
                X1 = cvtpk(sa0[rA + 2], sa0[rA + 3]);
                Y1 = cvtpk(sa0[rA + 6], sa0[rA + 7]);
            } else {
                const int rA = (ps & 1) * 8;
                X0 = cvtpk(sa1[rA + 0], sa1[rA + 1]);
                Y0 = cvtpk(sa1[rA + 4], sa1[rA + 5]);
                X1 = cvtpk(sa1[rA + 2], sa1[rA + 3]);
                Y1 = cvtpk(sa1[rA + 6], sa1[rA + 7]);
            }
            plswap(X0, Y0);   // X0 -> word m=0, Y0 -> word m=2
            plswap(X1, Y1);   // X1 -> word m=1, Y1 -> word m=3
            uint4 u = {X0, X1, Y0, Y1};
            pa[ps] = *(short8*)&u;
        }

        // PV: O[q][d] += P . V  (ps-outer / dt-inner: oacc0/oacc1 alternate)
        __builtin_amdgcn_s_setprio(1);
#pragma unroll
        for (int ps = 0; ps < 4; ++ps) {
            short8 vfr0 = *(const short8*)&Vc[(0 * 4 + ps) * 512 + l * 8];
            short8 vfr1 = *(const short8*)&Vc[(1 * 4 + ps) * 512 + l * 8];
            oacc0 = __builtin_amdgcn_mfma_f32_32x32x16_bf16(pa[ps], vfr0, oacc0, 0, 0, 0);
            oacc1 = __builtin_amdgcn_mfma_f32_32x32x16_bf16(pa[ps], vfr1, oacc1, 0, 0, 0);
        }
        __builtin_amdgcn_s_setprio(0);
    }

    // softmax denominator: own 32 p-values + partner half
    float lsum = (l4[0] + l4[1]) + (l4[2] + l4[3]);
    lsum += __shfl_xor(lsum, 32);
    const float inv = 1.0f / lsum;

    unsigned short* ob = Ob + (size_t)(b * S_ + qw) * D_ + h * DH_;
#pragma unroll
    for (int r = 0; r < 16; ++r) {
        const int qr = (r & 3) + 8 * (r >> 2) + 4 * lh;
        const float invr = __shfl(inv, qr);
        ob[(size_t)qr * D_ + lq] = f2bf(oacc0[r] * invr);
        ob[(size_t)qr * D_ + 32 + lq] = f2bf(oacc1[r] * invr);
    }
}

// ---------------------------------------------------------------------------
// launch
// ---------------------------------------------------------------------------
extern "C" void kernel_launch(void* const* d_in, const int* in_sizes, int n_in,
                              void* d_out, int out_size, void* d_ws, size_t ws_size,
                              hipStream_t stream) {
    const float* queries = (const float*)d_in[0];
    const float* patches = (const float*)d_in[1];
    const int* bounds    = (const int*)d_in[2];
    const float* wq = (const float*)d_in[3];
    const float* wk = (const float*)d_in[4];
    const float* wv = (const float*)d_in[5];
    const float* wo = (const float*)d_in[6];
    const float* bq = (const float*)d_in[7];
    const float* bk = (const float*)d_in[8];
    const float* bv = (const float*)d_in[9];
    const float* bo = (const float*)d_in[10];
    float* out = (float*)d_out;

    char* ws = (char*)d_ws;
    unsigned short* qb    = (unsigned short*)(ws + 0);          // 16777216
    unsigned short* pb    = (unsigned short*)(ws + 16777216);   // 4194304
    unsigned short* wqb   = (unsigned short*)(ws + 20971520);   // 2097152
    unsigned short* wkb   = (unsigned short*)(ws + 23068672);
    unsigned short* wvb   = (unsigned short*)(ws + 25165824);
    unsigned short* wob   = (unsigned short*)(ws + 27262976);
    unsigned short* Qbf   = (unsigned short*)(ws + 29360128);   // 16777216
    unsigned short* Kfr   = (unsigned short*)(ws + 46137344);   // 4194304
    unsigned short* Vfr   = (unsigned short*)(ws + 50331648);   // 4194304
    unsigned short* attnb = (unsigned short*)(ws + 54525952);   // 16777216
    int* pidx             = (int*)(ws + 71303168);              // 32768

    // 1. fused converts + cumsum
    xattn_convert_all<<<dim3(NCONV + B_), 256, 0, stream>>>(
        queries, patches, wq, wk, wv, wo, qb, pb, wqb, wkb, wvb, wob,
        bounds, pidx);
    // 2. fused Q/K/V projections (K/V emitted fragment-linear)
    xattn_gemm_qkv<<<dim3(8, 96), 256, 0, stream>>>(
        qb, pb, wqb, wkb, wvb, bq, bk, bv, Qbf, Kfr, Vfr);
    // 3. MFMA flash attention (32x32 swapped-QK, raw exp, chain-ILP 2)
    xattn_attn_mfma<<<dim3(S_ / 128, H_, B_), 256, 0, stream>>>(
        Qbf, Kfr, Vfr, pidx, attnb);
    // 4. output projection (fp32 out, dbuf pipeline)
    xattn_gemm_o<<<dim3(8, 64), 256, 0, stream>>>(attnb, wob, bo, out);
}